// Round 6
// baseline (1580.579 us; speedup 1.0000x reference)
//
#include <hip/hip_runtime.h>
#include <hip/hip_fp16.h>

#define HF 32
#define EPS 1e-5f
#define BSH 6
#define BSZ 64           // nodes per bucket (small -> 1563 blocks, high occupancy)
#define CH  16384        // edges per binning block (two-pass, L2-hot re-read)
#define SUBCAP 320       // per-XCD sub-segment capacity (mean fill 200, +8.5 sigma)
#define CAP (8*SUBCAP)   // bucket segment capacity (2560)

typedef int vi4 __attribute__((ext_vector_type(4)));

__device__ __forceinline__ float leaky(float v){ return fmaxf(v, 0.01f*v); }
__device__ __forceinline__ float elu1(float v){ return v > 0.f ? v : (expf(v)-1.f); }
__device__ __forceinline__ float sigmoidf(float v){ return 1.f/(1.f+expf(-v)); }

// LESSONS: nt stores on scattered writes -> 143MB writeback (r10). Scattered
// global atomics -> +84MB (r1). Degree-sorted node order -> block imbalance
// (r2). unsafeAtomicAdd(float*) lowers to the GLOBAL-AS fadd builtin -> LDS
// address via flat aperture, 12x slowdown, SQ_LDS_BANK_CONFLICT==0 proved no
// DS ops (r4). Plain atomicAdd on __shared__ float -> ds_add_f32 (used here).
__device__ __forceinline__ int4 nt_load_i4(const int* p){
    vi4 v = __builtin_nontemporal_load((const vi4*)p);
    return make_int4(v.x, v.y, v.z, v.w);
}

// accumulate 8 halfs (16B row quarter) into __shared__ f32 accumulator.
// a MUST point into __shared__ so addrspace inference emits ds_add_f32.
__device__ __forceinline__ void accum8_lds(float* a, float4 v){
    const __half2* p = (const __half2*)&v;
#pragma unroll
    for (int k = 0; k < 4; k++){
        float2 f = __half22float2(p[k]);
        atomicAdd(a + 2*k,     f.x);
        atomicAdd(a + 2*k + 1, f.y);
    }
}

// ===== fused: edge binning (two-pass, bin blocks FIRST) | MLP + BN stats ====
union SMem {
    struct {
        float sW1[3*HF]; float sB1[HF]; float sW2[HF*HF]; float sB2[HF];
        float sh[256][33];
    } mlp;
    struct { int lcnt[2048]; int lbase[2048]; int lpos[2048]; } bin;
};

__global__ __launch_bounds__(256)
void k_mlp_bin(const float* __restrict__ x,
               const float* __restrict__ w1, const float* __restrict__ b1,
               const float* __restrict__ w2, const float* __restrict__ b2,
               __half* __restrict__ h, float* __restrict__ stats,
               const int* __restrict__ src, const int* __restrict__ dst,
               int* __restrict__ gfill, int* __restrict__ ep,
               int N, int E, int B, int NC){
    __shared__ SMem sm;
    int t = threadIdx.x;
    if ((int)blockIdx.x < NC){
        // ------- binning: two-pass (count from nt stream, reserve, scatter) -
        int bid = blockIdx.x;
        for (int i = t; i < B; i += 256){ sm.bin.lcnt[i] = 0; sm.bin.lpos[i] = 0; }
        __syncthreads();
        int base = bid * CH;
        int xcd = bid & 7;
        bool full = (base + CH <= E);
        if (full){
            for (int i = 0; i < 16; i++){
                int4 d4 = nt_load_i4(dst + base + (t + i*256)*4);
                atomicAdd(&sm.bin.lcnt[d4.x >> BSH], 1);
                atomicAdd(&sm.bin.lcnt[d4.y >> BSH], 1);
                atomicAdd(&sm.bin.lcnt[d4.z >> BSH], 1);
                atomicAdd(&sm.bin.lcnt[d4.w >> BSH], 1);
            }
        } else {
            for (int i = 0; i < 64; i++){
                int e = base + t + i*256;
                if (e < E) atomicAdd(&sm.bin.lcnt[dst[e] >> BSH], 1);
            }
        }
        __syncthreads();
        // reserve contiguous range in this block's xcd sub-segment per bucket
        for (int i = t; i < B; i += 256){
            int c = sm.bin.lcnt[i];
            sm.bin.lbase[i] = c ? (i*CAP + xcd*SUBCAP + atomicAdd(&gfill[i*8 + xcd], c)) : 0;
        }
        __syncthreads();
        // scatter: re-read edges (L2-hot second pass)
        if (full){
            for (int i = 0; i < 16; i++){
                int idx = base + (t + i*256)*4;
                int4 d4 = *(const int4*)(dst + idx);
                int4 s4 = *(const int4*)(src + idx);
                int dd[4] = {d4.x, d4.y, d4.z, d4.w};
                int ss[4] = {s4.x, s4.y, s4.z, s4.w};
#pragma unroll
                for (int k = 0; k < 4; k++){
                    int bb = dd[k] >> BSH;
                    int p = sm.bin.lbase[bb] + atomicAdd(&sm.bin.lpos[bb], 1);
                    ep[p] = (ss[k] << BSH) | (dd[k] & (BSZ-1));
                }
            }
        } else {
            for (int i = 0; i < 64; i++){
                int e = base + t + i*256;
                if (e < E){
                    int d = dst[e], s = src[e];
                    int bb = d >> BSH;
                    int p = sm.bin.lbase[bb] + atomicAdd(&sm.bin.lpos[bb], 1);
                    ep[p] = (s << BSH) | (d & (BSZ-1));
                }
            }
        }
    } else {
        // ---------------- MLP + BN stats ----------------
        for (int i = t; i < 3*HF; i += 256) sm.mlp.sW1[i] = w1[i];
        if (t < HF){ sm.mlp.sB1[t] = b1[t]; sm.mlp.sB2[t] = b2[t]; }
        for (int i = t; i < HF*HF; i += 256) sm.mlp.sW2[i] = w2[i];
        __syncthreads();
        int n = (blockIdx.x - NC)*256 + t;
        float h2[HF];
        if (n < N){
            float x0 = x[(size_t)n*3], x1 = x[(size_t)n*3+1], x2 = x[(size_t)n*3+2];
            float h1[HF];
#pragma unroll
            for (int j = 0; j < HF; j++){
                float v = fmaf(x0, sm.mlp.sW1[j], fmaf(x1, sm.mlp.sW1[HF+j],
                          fmaf(x2, sm.mlp.sW1[2*HF+j], sm.mlp.sB1[j])));
                h1[j] = leaky(v);
            }
#pragma unroll
            for (int j = 0; j < HF; j++){
                float v = sm.mlp.sB2[j];
#pragma unroll
                for (int i = 0; i < HF; i++) v = fmaf(h1[i], sm.mlp.sW2[i*HF+j], v);
                h2[j] = leaky(v);
            }
            float4* hv = (float4*)(h + (size_t)n*HF);
#pragma unroll
            for (int jb = 0; jb < 4; jb++){
                __half2 hh[4];
#pragma unroll
                for (int k = 0; k < 4; k++)
                    hh[k] = __float22half2_rn(make_float2(h2[jb*8+2*k], h2[jb*8+2*k+1]));
                hv[jb] = *(float4*)hh;
            }
        } else {
#pragma unroll
            for (int j = 0; j < HF; j++) h2[j] = 0.f;
        }
#pragma unroll
        for (int j = 0; j < HF; j++) sm.mlp.sh[t][j] = h2[j];
        __syncthreads();
        int f = t & 31, g = t >> 5;
        float s = 0.f, ss = 0.f;
        for (int i = 0; i < 32; i++){
            float v = sm.mlp.sh[g*32 + i][f];
            s += v; ss += v*v;
        }
        __syncthreads();
        sm.mlp.sh[g][f] = s; sm.mlp.sh[8+g][f] = ss;
        __syncthreads();
        if (t < HF){
            float a = 0.f, b = 0.f;
#pragma unroll
            for (int g2 = 0; g2 < 8; g2++){ a += sm.mlp.sh[g2][t]; b += sm.mlp.sh[8+g2][t]; }
            atomicAdd(&stats[t], a);
            atomicAdd(&stats[HF+t], b);
        }
    }
}

// ===== per-bucket: degree count + in-place segment compaction + BN + t1 =====
// NO sort. lcnt[t] over the bucket's own edges IS deg. Segments staged in
// LDS, written back compact (prefix of the bucket's CAP range). BN+t1 with
// 4 threads/node, 8 features each.
__global__ __launch_bounds__(256)
void k_deg_t1(int* __restrict__ ep, const int* __restrict__ gfill,
              int* __restrict__ bcnt, float* __restrict__ dis,
              const __half* __restrict__ h, const float* __restrict__ stats,
              const float* __restrict__ gamma, const float* __restrict__ beta,
              const float* __restrict__ W, __half* __restrict__ tout,
              int N, int B){
    __shared__ union { int sep[CAP]; float hsh[BSZ][HF+1]; } u;
    __shared__ int lcnt[BSZ];
    __shared__ float sW[HF*HF];
    __shared__ float sscale[HF], sshift[HF];
    int t = threadIdx.x;
    int b = blockIdx.x;
    for (int i = t; i < HF*HF; i += 256) sW[i] = W[i];
    if (t < HF){
        float inv = 1.0f/(float)N;
        float mu  = stats[t]*inv;
        float var = stats[HF+t]*inv - mu*mu;
        float rs  = rsqrtf(var + EPS);
        float sc  = rs*gamma[t];
        sscale[t] = sc;
        sshift[t] = beta[t] - mu*sc;
    }
    if (t < BSZ) lcnt[t] = 0;
    int cx[8], coff[8], cnt = 0;
#pragma unroll
    for (int xx = 0; xx < 8; xx++){ cx[xx] = gfill[b*8 + xx]; coff[xx] = cnt; cnt += cx[xx]; }
    int base = b*CAP;
    __syncthreads();
#pragma unroll
    for (int xx = 0; xx < 8; xx++)
        for (int j = t; j < cx[xx]; j += 256) u.sep[coff[xx] + j] = ep[base + xx*SUBCAP + j];
    __syncthreads();
    for (int e = t; e < cnt; e += 256) atomicAdd(&lcnt[u.sep[e] & (BSZ-1)], 1);
    for (int e = t; e < cnt; e += 256) ep[base + e] = u.sep[e];   // compact
    if (t == 0) bcnt[b] = cnt;
    __syncthreads();
    // ------- BN + t1: 4 threads per node, 8 features each -------------------
    int nloc = t >> 2, q = t & 3;
    int n = b*BSZ + nloc;
    float dloc = 0.f;
    if (n < N){
        dloc = rsqrtf((float)lcnt[nloc] + 1.0f);
        if (q == 0) dis[n] = dloc;
        float4 raw = ((const float4*)h)[(size_t)n*4 + q];
        const __half2* p2 = (const __half2*)&raw;
#pragma unroll
        for (int k = 0; k < 4; k++){
            float2 f2 = __half22float2(p2[k]);
            int f = 8*q + 2*k;
            u.hsh[nloc][f]   = fmaf(f2.x, sscale[f],   sshift[f]);
            u.hsh[nloc][f+1] = fmaf(f2.y, sscale[f+1], sshift[f+1]);
        }
    }
    __syncthreads();
    if (n < N){
        int fo = 8*q;
        float o[8] = {0.f,0.f,0.f,0.f,0.f,0.f,0.f,0.f};
#pragma unroll
        for (int i = 0; i < HF; i++){
            float vi = u.hsh[nloc][i];
            float4 w0 = *(const float4*)&sW[i*HF + fo];
            float4 w1 = *(const float4*)&sW[i*HF + fo + 4];
            o[0] = fmaf(vi, w0.x, o[0]); o[1] = fmaf(vi, w0.y, o[1]);
            o[2] = fmaf(vi, w0.z, o[2]); o[3] = fmaf(vi, w0.w, o[3]);
            o[4] = fmaf(vi, w1.x, o[4]); o[5] = fmaf(vi, w1.y, o[5]);
            o[6] = fmaf(vi, w1.z, o[6]); o[7] = fmaf(vi, w1.w, o[7]);
        }
        __half2 hh[4];
#pragma unroll
        for (int k = 0; k < 4; k++)
            hh[k] = __float22half2_rn(make_float2(o[2*k]*dloc, o[2*k+1]*dloc));
        ((float4*)tout)[(size_t)n*4 + q] = *(float4*)hh;
    }
}

// ===== edge-parallel gather per bucket (ds_add_f32) + finish + transform ====
// 64 groups of 4 lanes; each group one edge: lanes load 16B of the 64B src
// row, convert, ds_add_f32 into acc[dstloc][]. Perfectly balanced, no CSR.
__global__ __launch_bounds__(256)
void k_gather_t(const __half* __restrict__ tin, const int* __restrict__ ep,
                const int* __restrict__ bcnt, const float* __restrict__ dis,
                const float* __restrict__ bias, const float* __restrict__ W,
                __half* __restrict__ tout, int N){
    __shared__ float acc[BSZ][HF+1];
    __shared__ float sW[HF*HF];
    int t = threadIdx.x, b = blockIdx.x;
    for (int i = t; i < HF*HF; i += 256) sW[i] = W[i];
    for (int i = t; i < BSZ*(HF+1); i += 256) ((float*)acc)[i] = 0.f;
    int cnt = bcnt[b];
    int base = b*CAP;
    __syncthreads();
    int g = t >> 2, l = t & 3;
    const float4* tv = (const float4*)tin;
    int j = g;
    for (; j + 64 < cnt; j += 128){
        int p0 = ep[base + j], p1 = ep[base + j + 64];
        float4 r0 = tv[(size_t)(p0 >> BSH)*4 + l];
        float4 r1 = tv[(size_t)(p1 >> BSH)*4 + l];
        accum8_lds(&acc[p0 & (BSZ-1)][8*l], r0);
        accum8_lds(&acc[p1 & (BSZ-1)][8*l], r1);
    }
    for (; j < cnt; j += 64){
        int p0 = ep[base + j];
        float4 r0 = tv[(size_t)(p0 >> BSH)*4 + l];
        accum8_lds(&acc[p0 & (BSZ-1)][8*l], r0);
    }
    __syncthreads();
    // ------- finish: 4 threads/node: self + dis + bias + elu, in place ------
    int nloc = t >> 2, q = t & 3;
    int n = b*BSZ + nloc;
    float dv = 0.f;
    if (n < N){
        dv = dis[n];
        float4 s0 = tv[(size_t)n*4 + q];
        const __half2* ph = (const __half2*)&s0;
#pragma unroll
        for (int k = 0; k < 4; k++){
            float2 f2 = __half22float2(ph[k]);
            int f = 8*q + 2*k;
            acc[nloc][f]   = elu1(fmaf(dv, acc[nloc][f]   + f2.x, bias[f]));
            acc[nloc][f+1] = elu1(fmaf(dv, acc[nloc][f+1] + f2.y, bias[f+1]));
        }
    }
    __syncthreads();
    // ------- transform: o = (hnext @ W) * dis, fp16 store -------------------
    if (n < N){
        int fo = 8*q;
        float o[8] = {0.f,0.f,0.f,0.f,0.f,0.f,0.f,0.f};
#pragma unroll
        for (int i = 0; i < HF; i++){
            float hv = acc[nloc][i];
            float4 w0 = *(const float4*)&sW[i*HF + fo];
            float4 w1 = *(const float4*)&sW[i*HF + fo + 4];
            o[0] = fmaf(hv, w0.x, o[0]); o[1] = fmaf(hv, w0.y, o[1]);
            o[2] = fmaf(hv, w0.z, o[2]); o[3] = fmaf(hv, w0.w, o[3]);
            o[4] = fmaf(hv, w1.x, o[4]); o[5] = fmaf(hv, w1.y, o[5]);
            o[6] = fmaf(hv, w1.z, o[6]); o[7] = fmaf(hv, w1.w, o[7]);
        }
        __half2 hh[4];
#pragma unroll
        for (int k = 0; k < 4; k++)
            hh[k] = __float22half2_rn(make_float2(o[2*k]*dv, o[2*k+1]*dv));
        ((float4*)tout)[(size_t)n*4 + q] = *(float4*)hh;
    }
}

// ===== edge-parallel gather + elu + output MLP + sigmoid col 0 ==============
__global__ __launch_bounds__(256)
void k_gather_out(const __half* __restrict__ tin, const int* __restrict__ ep,
                  const int* __restrict__ bcnt, const float* __restrict__ dis,
                  const float* __restrict__ bg3,
                  const float* __restrict__ wo1, const float* __restrict__ bo1,
                  const float* __restrict__ wo2, const float* __restrict__ bo2,
                  const float* __restrict__ wo3, const float* __restrict__ bo3,
                  float* __restrict__ out, int N){
    __shared__ float acc[BSZ][HF+1];
    __shared__ float sW1[HF*HF], sW2[HF*HF], sW3[HF*4];
    int t = threadIdx.x, b = blockIdx.x;
    for (int i = t; i < HF*HF; i += 256){ sW1[i] = wo1[i]; sW2[i] = wo2[i]; }
    if (t < HF*4) sW3[t] = wo3[t];
    for (int i = t; i < BSZ*(HF+1); i += 256) ((float*)acc)[i] = 0.f;
    int cnt = bcnt[b];
    int base = b*CAP;
    __syncthreads();
    int g = t >> 2, l = t & 3;
    const float4* tv = (const float4*)tin;
    int j = g;
    for (; j + 64 < cnt; j += 128){
        int p0 = ep[base + j], p1 = ep[base + j + 64];
        float4 r0 = tv[(size_t)(p0 >> BSH)*4 + l];
        float4 r1 = tv[(size_t)(p1 >> BSH)*4 + l];
        accum8_lds(&acc[p0 & (BSZ-1)][8*l], r0);
        accum8_lds(&acc[p1 & (BSZ-1)][8*l], r1);
    }
    for (; j < cnt; j += 64){
        int p0 = ep[base + j];
        float4 r0 = tv[(size_t)(p0 >> BSH)*4 + l];
        accum8_lds(&acc[p0 & (BSZ-1)][8*l], r0);
    }
    __syncthreads();
    int nloc = t >> 2, q = t & 3;
    int n = b*BSZ + nloc;
    // finish: self + dis + bg3 + elu -> acc (h for the output MLP)
    if (n < N){
        float dv = dis[n];
        float4 s0 = tv[(size_t)n*4 + q];
        const __half2* ph = (const __half2*)&s0;
#pragma unroll
        for (int k = 0; k < 4; k++){
            float2 f2 = __half22float2(ph[k]);
            int f = 8*q + 2*k;
            acc[nloc][f]   = elu1(fmaf(dv, acc[nloc][f]   + f2.x, bg3[f]));
            acc[nloc][f+1] = elu1(fmaf(dv, acc[nloc][f+1] + f2.y, bg3[f+1]));
        }
    }
    __syncthreads();
    // o1 = leaky(h @ Wo1 + bo1)
    float o1[8];
    if (n < N){
        int fo = 8*q;
#pragma unroll
        for (int c = 0; c < 8; c++) o1[c] = bo1[fo + c];
#pragma unroll
        for (int i = 0; i < HF; i++){
            float hv = acc[nloc][i];
            float4 w0 = *(const float4*)&sW1[i*HF + fo];
            float4 w1 = *(const float4*)&sW1[i*HF + fo + 4];
            o1[0] = fmaf(hv, w0.x, o1[0]); o1[1] = fmaf(hv, w0.y, o1[1]);
            o1[2] = fmaf(hv, w0.z, o1[2]); o1[3] = fmaf(hv, w0.w, o1[3]);
            o1[4] = fmaf(hv, w1.x, o1[4]); o1[5] = fmaf(hv, w1.y, o1[5]);
            o1[6] = fmaf(hv, w1.z, o1[6]); o1[7] = fmaf(hv, w1.w, o1[7]);
        }
    }
    __syncthreads();
    if (n < N){
        int fo = 8*q;
#pragma unroll
        for (int c = 0; c < 8; c++) acc[nloc][fo + c] = leaky(o1[c]);
    }
    __syncthreads();
    // o2 = leaky(o1 @ Wo2 + bo2)
    float o2[8];
    if (n < N){
        int fo = 8*q;
#pragma unroll
        for (int c = 0; c < 8; c++) o2[c] = bo2[fo + c];
#pragma unroll
        for (int i = 0; i < HF; i++){
            float hv = acc[nloc][i];
            float4 w0 = *(const float4*)&sW2[i*HF + fo];
            float4 w1 = *(const float4*)&sW2[i*HF + fo + 4];
            o2[0] = fmaf(hv, w0.x, o2[0]); o2[1] = fmaf(hv, w0.y, o2[1]);
            o2[2] = fmaf(hv, w0.z, o2[2]); o2[3] = fmaf(hv, w0.w, o2[3]);
            o2[4] = fmaf(hv, w1.x, o2[4]); o2[5] = fmaf(hv, w1.y, o2[5]);
            o2[6] = fmaf(hv, w1.z, o2[6]); o2[7] = fmaf(hv, w1.w, o2[7]);
        }
    }
    __syncthreads();
    if (n < N){
        int fo = 8*q;
#pragma unroll
        for (int c = 0; c < 8; c++) acc[nloc][fo + c] = leaky(o2[c]);
    }
    __syncthreads();
    // final: 4 threads/node, 1 output each
    if (n < N){
        float v = bo3[q];
#pragma unroll
        for (int i = 0; i < HF; i++) v = fmaf(acc[nloc][i], sW3[i*4 + q], v);
        if (q == 0) v = sigmoidf(v);
        out[(size_t)n*4 + q] = v;
    }
}

extern "C" void kernel_launch(void* const* d_in, const int* in_sizes, int n_in,
                              void* d_out, int out_size, void* d_ws, size_t ws_size,
                              hipStream_t stream) {
    const float* x     = (const float*)d_in[0];
    const float* w_in1 = (const float*)d_in[1];
    const float* b_in1 = (const float*)d_in[2];
    const float* w_in2 = (const float*)d_in[3];
    const float* b_in2 = (const float*)d_in[4];
    const float* gamma = (const float*)d_in[5];
    const float* beta  = (const float*)d_in[6];
    const float* wg1   = (const float*)d_in[7];
    const float* bg1   = (const float*)d_in[8];
    const float* wg2   = (const float*)d_in[9];
    const float* bg2   = (const float*)d_in[10];
    const float* wg3   = (const float*)d_in[11];
    const float* bg3   = (const float*)d_in[12];
    const float* wo1   = (const float*)d_in[13];
    const float* bo1   = (const float*)d_in[14];
    const float* wo2   = (const float*)d_in[15];
    const float* bo2   = (const float*)d_in[16];
    const float* wo3   = (const float*)d_in[17];
    const float* bo3   = (const float*)d_in[18];
    const int*   ei    = (const int*)d_in[19];

    int N = in_sizes[0] / 3;
    int E = in_sizes[19] / 2;
    int B = (N + BSZ - 1) >> BSH;          // buckets (1563; bin arrays hold 2048)

    char* w = (char*)d_ws;
    size_t o = 0;
    auto alloc = [&](size_t bytes){ size_t r = o; o = (o + bytes + 255) & ~(size_t)255; return r; };
    // ---- zeroed region ----
    float* stats = (float*)(w + alloc(2*HF*sizeof(float)));
    int*   gfill = (int*)  (w + alloc((size_t)B*8*4));
    size_t zero_bytes = o;
    // ---- rest ----
    int*   bcnt  = (int*)  (w + alloc((size_t)B*4));
    float* dis   = (float*)(w + alloc((size_t)N*4));
    int*   ep    = (int*)  (w + alloc((size_t)B*CAP*4));
    __half* bufH = (__half*)(w + alloc((size_t)N*HF*2));
    __half* tA   = (__half*)(w + alloc((size_t)N*HF*2));
    __half* tB   = (__half*)(w + alloc((size_t)N*HF*2));

    hipMemsetAsync(d_ws, 0, zero_bytes, stream);

    const int* src = ei;
    const int* dst = ei + E;
    int NB1 = (N + 255) / 256;
    int NC  = (E + CH - 1) / CH;

    k_mlp_bin<<<NC + NB1, 256, 0, stream>>>(x, w_in1, b_in1, w_in2, b_in2, bufH, stats,
                                            src, dst, gfill, ep, N, E, B, NC);
    k_deg_t1<<<B, 256, 0, stream>>>(ep, gfill, bcnt, dis,
                                    bufH, stats, gamma, beta, wg1, tA, N, B);
    k_gather_t<<<B, 256, 0, stream>>>(tA, ep, bcnt, dis, bg1, wg2, tB, N);
    k_gather_t<<<B, 256, 0, stream>>>(tB, ep, bcnt, dis, bg2, wg3, tA, N);
    k_gather_out<<<B, 256, 0, stream>>>(tA, ep, bcnt, dis, bg3,
                                        wo1, bo1, wo2, bo2, wo3, bo3, (float*)d_out, N);
}

// Round 7
// 964.542 us; speedup vs baseline: 1.6387x; 1.6387x over previous
//
#include <hip/hip_runtime.h>
#include <hip/hip_fp16.h>

#define HF 32
#define EPS 1e-5f
#define BSH 7
#define BSZ 128          // nodes per bucket
#define CH  16384        // edges per binning block (two-pass, L2-hot re-read)
#define SUBCAP 512       // per-XCD sub-segment capacity
#define CAP (8*SUBCAP)   // bucket segment capacity (4096)

typedef int vi4 __attribute__((ext_vector_type(4)));

__device__ __forceinline__ float leaky(float v){ return fmaxf(v, 0.01f*v); }
__device__ __forceinline__ float elu1(float v){ return v > 0.f ? v : (expf(v)-1.f); }
__device__ __forceinline__ float sigmoidf(float v){ return 1.f/(1.f+expf(-v)); }

// LESSONS: nt stores on scattered writes -> 143MB writeback (r10). Scattered
// global atomics -> +84MB (r1). Degree-sorted node order -> imbalance (r2).
// FP atomics into LDS (any spelling) -> flat/CAS path, 10-30x slowdown
// (r4: unsafeAtomicAdd, r6: atomicAdd on __shared__). Only INT atomics in
// LDS; only {stats, gfill, barrier} atomics in global.
__device__ __forceinline__ int4 nt_load_i4(const int* p){
    vi4 v = __builtin_nontemporal_load((const vi4*)p);
    return make_int4(v.x, v.y, v.z, v.w);
}

__device__ __forceinline__ void addrow8(float* a, float4 v){
    const __half2* p = (const __half2*)&v;
#pragma unroll
    for (int k = 0; k < 4; k++){
        float2 f = __half22float2(p[k]);
        a[2*k] += f.x; a[2*k+1] += f.y;
    }
}
__device__ __forceinline__ float4 h2add4f(float4 a, float4 b){
    __half2* pa = (__half2*)&a; __half2* pb = (__half2*)&b;
    float4 r; __half2* pr = (__half2*)&r;
#pragma unroll
    for (int k = 0; k < 4; k++) pr[k] = __hadd2(pa[k], pb[k]);
    return r;
}

// LDS union across all phases; max member = mlp (38.5 KB) -> 4 blocks/CU.
union FSM {
    struct {
        float sW1[3*HF]; float sB1[HF]; float sW2[HF*HF]; float sB2[HF];
        float sh[256][33];
    } mlp;
    struct { int lcnt[1024]; int lbase[1024]; int lpos[1024]; } bin;
    struct {
        int sep[CAP]; int lcnt[128]; int lpre[128]; int lfill[128];
        float sW[HF*HF]; float sscale[HF]; float sshift[HF];
    } csr;
    struct { float sW[HF*HF]; float sh[32][33]; } gt;
    struct { float sW1[HF*HF]; float sW2[HF*HF]; float sW3[HF*4];
             float sh[32][33]; float sh2[32][33]; } go;
};

// device-wide barrier: all blocks resident (grid sized by occupancy query).
// Agent-scope fences force L2 writeback/invalidate across XCDs; flags are
// agent-scope atomics (RMW/loads go to the coherence point, not stale L2).
__device__ __forceinline__ void grid_bar(int* cnt, int* gen){
    __syncthreads();
    if (threadIdx.x == 0){
        __threadfence();   // release: writeback this XCD's L2
        int g = __hip_atomic_load(gen, __ATOMIC_RELAXED, __HIP_MEMORY_SCOPE_AGENT);
        int prev = __hip_atomic_fetch_add(cnt, 1, __ATOMIC_ACQ_REL, __HIP_MEMORY_SCOPE_AGENT);
        if (prev == (int)gridDim.x - 1){
            __hip_atomic_store(cnt, 0, __ATOMIC_RELAXED, __HIP_MEMORY_SCOPE_AGENT);
            __hip_atomic_fetch_add(gen, 1, __ATOMIC_RELEASE, __HIP_MEMORY_SCOPE_AGENT);
        } else {
            while (__hip_atomic_load(gen, __ATOMIC_ACQUIRE, __HIP_MEMORY_SCOPE_AGENT) == g)
                __builtin_amdgcn_s_sleep(2);
        }
        __threadfence();   // acquire: invalidate this XCD's L2
    }
    __syncthreads();
}

__global__ __launch_bounds__(256, 4)
void k_fused(const float* __restrict__ x,
             const float* __restrict__ w_in1, const float* __restrict__ b_in1,
             const float* __restrict__ w_in2, const float* __restrict__ b_in2,
             const float* __restrict__ gamma, const float* __restrict__ beta,
             const float* __restrict__ wg1, const float* __restrict__ bg1,
             const float* __restrict__ wg2, const float* __restrict__ bg2,
             const float* __restrict__ wg3, const float* __restrict__ bg3,
             const float* __restrict__ wo1, const float* __restrict__ bo1,
             const float* __restrict__ wo2, const float* __restrict__ bo2,
             const float* __restrict__ wo3, const float* __restrict__ bo3,
             const int* __restrict__ src, const int* __restrict__ dst,
             float* __restrict__ stats, int* __restrict__ gfill,
             int* __restrict__ barv,
             int2* __restrict__ rowp2, float* __restrict__ dis, int* __restrict__ ep,
             __half* __restrict__ bufH, __half* __restrict__ tA, __half* __restrict__ tB,
             float* __restrict__ out,
             int N, int E, int B, int NC, int NB1, int GN)
{
    __shared__ FSM sm;
    int t = threadIdx.x;
    int blk = blockIdx.x, nblk = gridDim.x;

    // ============ phase 0: edge binning | input MLP + BN stats ============
    for (int w = blk; w < NC + NB1; w += nblk){
        __syncthreads();
        if (w < NC){
            int bid = w;
            for (int i = t; i < B; i += 256){ sm.bin.lcnt[i] = 0; sm.bin.lpos[i] = 0; }
            __syncthreads();
            int base = bid * CH;
            int xcd = bid & 7;
            bool full = (base + CH <= E);
            if (full){
                for (int i = 0; i < 16; i++){
                    int4 d4 = nt_load_i4(dst + base + (t + i*256)*4);
                    atomicAdd(&sm.bin.lcnt[d4.x >> BSH], 1);
                    atomicAdd(&sm.bin.lcnt[d4.y >> BSH], 1);
                    atomicAdd(&sm.bin.lcnt[d4.z >> BSH], 1);
                    atomicAdd(&sm.bin.lcnt[d4.w >> BSH], 1);
                }
            } else {
                for (int i = 0; i < 64; i++){
                    int e = base + t + i*256;
                    if (e < E) atomicAdd(&sm.bin.lcnt[dst[e] >> BSH], 1);
                }
            }
            __syncthreads();
            for (int i = t; i < B; i += 256){
                int c = sm.bin.lcnt[i];
                sm.bin.lbase[i] = c ? (i*CAP + xcd*SUBCAP + atomicAdd(&gfill[i*8 + xcd], c)) : 0;
            }
            __syncthreads();
            if (full){
                for (int i = 0; i < 16; i++){
                    int idx = base + (t + i*256)*4;
                    int4 d4 = *(const int4*)(dst + idx);
                    int4 s4 = *(const int4*)(src + idx);
                    int dd[4] = {d4.x, d4.y, d4.z, d4.w};
                    int ss[4] = {s4.x, s4.y, s4.z, s4.w};
#pragma unroll
                    for (int k = 0; k < 4; k++){
                        int bb = dd[k] >> BSH;
                        int p = sm.bin.lbase[bb] + atomicAdd(&sm.bin.lpos[bb], 1);
                        ep[p] = (ss[k] << BSH) | (dd[k] & (BSZ-1));
                    }
                }
            } else {
                for (int i = 0; i < 64; i++){
                    int e = base + t + i*256;
                    if (e < E){
                        int d = dst[e], s = src[e];
                        int bb = d >> BSH;
                        int p = sm.bin.lbase[bb] + atomicAdd(&sm.bin.lpos[bb], 1);
                        ep[p] = (s << BSH) | (d & (BSZ-1));
                    }
                }
            }
        } else {
            // ---- MLP + BN stats ----
            for (int i = t; i < 3*HF; i += 256) sm.mlp.sW1[i] = w_in1[i];
            if (t < HF){ sm.mlp.sB1[t] = b_in1[t]; sm.mlp.sB2[t] = b_in2[t]; }
            for (int i = t; i < HF*HF; i += 256) sm.mlp.sW2[i] = w_in2[i];
            __syncthreads();
            int n = (w - NC)*256 + t;
            float h2[HF];
            if (n < N){
                float x0 = x[(size_t)n*3], x1 = x[(size_t)n*3+1], x2 = x[(size_t)n*3+2];
                float h1[HF];
#pragma unroll
                for (int j = 0; j < HF; j++){
                    float v = fmaf(x0, sm.mlp.sW1[j], fmaf(x1, sm.mlp.sW1[HF+j],
                              fmaf(x2, sm.mlp.sW1[2*HF+j], sm.mlp.sB1[j])));
                    h1[j] = leaky(v);
                }
#pragma unroll
                for (int j = 0; j < HF; j++){
                    float v = sm.mlp.sB2[j];
#pragma unroll
                    for (int i = 0; i < HF; i++) v = fmaf(h1[i], sm.mlp.sW2[i*HF+j], v);
                    h2[j] = leaky(v);
                }
                float4* hv = (float4*)(bufH + (size_t)n*HF);
#pragma unroll
                for (int jb = 0; jb < 4; jb++){
                    __half2 hh[4];
#pragma unroll
                    for (int k = 0; k < 4; k++)
                        hh[k] = __float22half2_rn(make_float2(h2[jb*8+2*k], h2[jb*8+2*k+1]));
                    hv[jb] = *(float4*)hh;
                }
            } else {
#pragma unroll
                for (int j = 0; j < HF; j++) h2[j] = 0.f;
            }
#pragma unroll
            for (int j = 0; j < HF; j++) sm.mlp.sh[t][j] = h2[j];
            __syncthreads();
            int f = t & 31, g = t >> 5;
            float s = 0.f, ss = 0.f;
            for (int i = 0; i < 32; i++){
                float v = sm.mlp.sh[g*32 + i][f];
                s += v; ss += v*v;
            }
            __syncthreads();
            sm.mlp.sh[g][f] = s; sm.mlp.sh[8+g][f] = ss;
            __syncthreads();
            if (t < HF){
                float a = 0.f, b = 0.f;
#pragma unroll
                for (int g2 = 0; g2 < 8; g2++){ a += sm.mlp.sh[g2][t]; b += sm.mlp.sh[8+g2][t]; }
                atomicAdd(&stats[t], a);
                atomicAdd(&stats[HF+t], b);
            }
        }
    }
    grid_bar(barv, barv + 64);

    // ============ phase 1: per-bucket CSR sort + BN + t1 ============
    for (int i = t; i < HF*HF; i += 256) sm.csr.sW[i] = wg1[i];
    if (t < HF){
        float inv = 1.0f/(float)N;
        float mu  = stats[t]*inv;
        float var = stats[HF+t]*inv - mu*mu;
        float rs  = rsqrtf(var + EPS);
        float sc  = rs*gamma[t];
        sm.csr.sscale[t] = sc;
        sm.csr.sshift[t] = beta[t] - mu*sc;
    }
    for (int b = blk; b < B; b += nblk){
        __syncthreads();
        if (t < 128){ sm.csr.lcnt[t] = 0; sm.csr.lfill[t] = 0; }
        int cx[8], coff[8], cnt = 0;
#pragma unroll
        for (int xx = 0; xx < 8; xx++){ cx[xx] = gfill[b*8 + xx]; coff[xx] = cnt; cnt += cx[xx]; }
        int base = b*CAP;
        __syncthreads();
#pragma unroll
        for (int xx = 0; xx < 8; xx++)
            for (int j = t; j < cx[xx]; j += 256) sm.csr.sep[coff[xx] + j] = ep[base + xx*SUBCAP + j];
        __syncthreads();
        for (int e = t; e < cnt; e += 256) atomicAdd(&sm.csr.lcnt[sm.csr.sep[e] & (BSZ-1)], 1);
        __syncthreads();
        if (t < 128){
            int dg = sm.csr.lcnt[t];
            int pre = 0;
            for (int j = 0; j < t; j++) pre += sm.csr.lcnt[j];
            sm.csr.lpre[t] = pre;
            int n = b*BSZ + t;
            if (n < N){
                rowp2[n] = make_int2(base + pre, base + pre + dg);
                dis[n]   = rsqrtf((float)dg + 1.0f);
            }
        }
        __syncthreads();
        for (int e = t; e < cnt; e += 256){
            int val = sm.csr.sep[e];
            int d2 = val & (BSZ-1);
            int p = sm.csr.lpre[d2] + atomicAdd(&sm.csr.lfill[d2], 1);
            ep[base + p] = val >> BSH;
        }
        // BN + t1: 2 threads/node, 16 features each
        int nloc = t >> 1, fh = (t & 1) * 16;
        int n = b*BSZ + nloc;
        if (n < N){
            float dloc = rsqrtf((float)sm.csr.lcnt[nloc] + 1.0f);
            const float4* hv4 = (const float4*)bufH + (size_t)n*4;
            float v[HF];
#pragma unroll
            for (int k = 0; k < 4; k++){
                float4 raw = hv4[k];
                const __half2* p2 = (const __half2*)&raw;
#pragma unroll
                for (int q = 0; q < 4; q++){
                    float2 f2 = __half22float2(p2[q]);
                    v[8*k + 2*q]     = f2.x;
                    v[8*k + 2*q + 1] = f2.y;
                }
            }
#pragma unroll
            for (int f = 0; f < HF; f++) v[f] = fmaf(v[f], sm.csr.sscale[f], sm.csr.sshift[f]);
            float o[16];
#pragma unroll
            for (int j = 0; j < 16; j++) o[j] = 0.f;
#pragma unroll
            for (int i = 0; i < HF; i++){
                float vi = v[i];
#pragma unroll
                for (int j4 = 0; j4 < 4; j4++){
                    float4 w4 = *(const float4*)&sm.csr.sW[i*HF + fh + 4*j4];
                    o[4*j4]   = fmaf(vi, w4.x, o[4*j4]);
                    o[4*j4+1] = fmaf(vi, w4.y, o[4*j4+1]);
                    o[4*j4+2] = fmaf(vi, w4.z, o[4*j4+2]);
                    o[4*j4+3] = fmaf(vi, w4.w, o[4*j4+3]);
                }
            }
            float4* ov = (float4*)tA + (size_t)n*4 + (t & 1)*2;
#pragma unroll
            for (int k = 0; k < 2; k++){
                __half2 hh[4];
#pragma unroll
                for (int q = 0; q < 4; q++)
                    hh[q] = __float22half2_rn(make_float2(o[8*k+2*q]*dloc, o[8*k+2*q+1]*dloc));
                ov[k] = *(float4*)hh;
            }
        }
    }
    grid_bar(barv, barv + 64);

    // ============ phases 2-3: gather + transform (two GCN layers) ============
    {
        const __half* gin = tA; __half* gouth = tB;
        const float* gbias = bg1; const float* gw = wg2;
        for (int layer = 0; layer < 2; layer++){
            for (int i = t; i < HF*HF; i += 256) sm.gt.sW[i] = gw[i];
            for (int c = blk; c < GN; c += nblk){
                __syncthreads();
                int node = t >> 3, l2 = t & 7, l = l2 & 3, hfv = l2 >> 2;
                int n = c*32 + node;
                float acc[8] = {0.f,0.f,0.f,0.f,0.f,0.f,0.f,0.f};
                float d = 0.f;
                const float4* tv = (const float4*)gin;
                if (n < N){
                    if (hfv == 0) addrow8(acc, tv[(size_t)n*4 + l]);
                    int2 r = rowp2[n];
                    int e0 = r.x, e1 = r.y;
                    int ea = (e0 + 3) & ~3; if (ea > e1) ea = e1;
                    if (hfv == 0) for (int e = e0; e < ea; e++) addrow8(acc, tv[(size_t)ep[e]*4 + l]);
                    int nch = (e1 - ea) >> 2;
                    int c2 = hfv;
                    for (; c2 + 2 < nch; c2 += 4){
                        int4 a4 = nt_load_i4(&ep[ea + 4*c2]);
                        int4 b4 = nt_load_i4(&ep[ea + 4*(c2+2)]);
                        float4 v0 = tv[(size_t)a4.x*4 + l];
                        float4 v1 = tv[(size_t)a4.y*4 + l];
                        float4 v2 = tv[(size_t)a4.z*4 + l];
                        float4 v3 = tv[(size_t)a4.w*4 + l];
                        float4 v4 = tv[(size_t)b4.x*4 + l];
                        float4 v5 = tv[(size_t)b4.y*4 + l];
                        float4 v6 = tv[(size_t)b4.z*4 + l];
                        float4 v7 = tv[(size_t)b4.w*4 + l];
                        addrow8(acc, h2add4f(h2add4f(v0, v1), h2add4f(v2, v3)));
                        addrow8(acc, h2add4f(h2add4f(v4, v5), h2add4f(v6, v7)));
                    }
                    for (; c2 < nch; c2 += 2){
                        int4 s4 = nt_load_i4(&ep[ea + 4*c2]);
                        float4 v0 = tv[(size_t)s4.x*4 + l];
                        float4 v1 = tv[(size_t)s4.y*4 + l];
                        float4 v2 = tv[(size_t)s4.z*4 + l];
                        float4 v3 = tv[(size_t)s4.w*4 + l];
                        addrow8(acc, h2add4f(h2add4f(v0, v1), h2add4f(v2, v3)));
                    }
                    if (hfv == 1) for (int e = ea + 4*nch; e < e1; e++) addrow8(acc, tv[(size_t)ep[e]*4 + l]);
#pragma unroll
                    for (int cc = 0; cc < 8; cc++) acc[cc] += __shfl_xor(acc[cc], 4);
                    d = dis[n];
#pragma unroll
                    for (int cc = 0; cc < 8; cc++)
                        acc[cc] = elu1(fmaf(d, acc[cc], gbias[8*l + cc]));
                }
                __syncthreads();
                if (hfv == 0){
#pragma unroll
                    for (int cc = 0; cc < 8; cc++) sm.gt.sh[node][8*l + cc] = acc[cc];
                }
                __syncthreads();
                float o[4] = {0.f,0.f,0.f,0.f};
#pragma unroll
                for (int i = 0; i < HF; i++){
                    float hvv = sm.gt.sh[node][i];
                    float4 w4 = *(const float4*)&sm.gt.sW[i*HF + 4*l2];
                    o[0] = fmaf(hvv, w4.x, o[0]); o[1] = fmaf(hvv, w4.y, o[1]);
                    o[2] = fmaf(hvv, w4.z, o[2]); o[3] = fmaf(hvv, w4.w, o[3]);
                }
                if (n < N){
                    __half2 hh[2];
                    hh[0] = __float22half2_rn(make_float2(o[0]*d, o[1]*d));
                    hh[1] = __float22half2_rn(make_float2(o[2]*d, o[3]*d));
                    ((float2*)gouth)[(size_t)n*8 + l2] = *(float2*)hh;
                }
            }
            grid_bar(barv, barv + 64);
            gin = tB; gouth = tA; gbias = bg2; gw = wg3;
        }
    }

    // ============ phase 4: gather layer3 + output MLP + sigmoid ============
    for (int i = t; i < HF*HF; i += 256){ sm.go.sW1[i] = wo1[i]; sm.go.sW2[i] = wo2[i]; }
    if (t < HF*4) sm.go.sW3[t] = wo3[t];
    for (int c = blk; c < GN; c += nblk){
        __syncthreads();
        int node = t >> 3, l2 = t & 7, l = l2 & 3, hfv = l2 >> 2;
        int n = c*32 + node;
        float acc[8] = {0.f,0.f,0.f,0.f,0.f,0.f,0.f,0.f};
        const float4* tv = (const float4*)tA;
        if (n < N){
            if (hfv == 0) addrow8(acc, tv[(size_t)n*4 + l]);
            int2 r = rowp2[n];
            int e0 = r.x, e1 = r.y;
            int ea = (e0 + 3) & ~3; if (ea > e1) ea = e1;
            if (hfv == 0) for (int e = e0; e < ea; e++) addrow8(acc, tv[(size_t)ep[e]*4 + l]);
            int nch = (e1 - ea) >> 2;
            int c2 = hfv;
            for (; c2 + 2 < nch; c2 += 4){
                int4 a4 = nt_load_i4(&ep[ea + 4*c2]);
                int4 b4 = nt_load_i4(&ep[ea + 4*(c2+2)]);
                float4 v0 = tv[(size_t)a4.x*4 + l];
                float4 v1 = tv[(size_t)a4.y*4 + l];
                float4 v2 = tv[(size_t)a4.z*4 + l];
                float4 v3 = tv[(size_t)a4.w*4 + l];
                float4 v4 = tv[(size_t)b4.x*4 + l];
                float4 v5 = tv[(size_t)b4.y*4 + l];
                float4 v6 = tv[(size_t)b4.z*4 + l];
                float4 v7 = tv[(size_t)b4.w*4 + l];
                addrow8(acc, h2add4f(h2add4f(v0, v1), h2add4f(v2, v3)));
                addrow8(acc, h2add4f(h2add4f(v4, v5), h2add4f(v6, v7)));
            }
            for (; c2 < nch; c2 += 2){
                int4 s4 = nt_load_i4(&ep[ea + 4*c2]);
                float4 v0 = tv[(size_t)s4.x*4 + l];
                float4 v1 = tv[(size_t)s4.y*4 + l];
                float4 v2 = tv[(size_t)s4.z*4 + l];
                float4 v3 = tv[(size_t)s4.w*4 + l];
                addrow8(acc, h2add4f(h2add4f(v0, v1), h2add4f(v2, v3)));
            }
            if (hfv == 1) for (int e = ea + 4*nch; e < e1; e++) addrow8(acc, tv[(size_t)ep[e]*4 + l]);
#pragma unroll
            for (int cc = 0; cc < 8; cc++) acc[cc] += __shfl_xor(acc[cc], 4);
            float d = dis[n];
#pragma unroll
            for (int cc = 0; cc < 8; cc++)
                acc[cc] = elu1(fmaf(d, acc[cc], bg3[8*l + cc]));
        }
        __syncthreads();
        if (hfv == 0){
#pragma unroll
            for (int cc = 0; cc < 8; cc++) sm.go.sh[node][8*l + cc] = acc[cc];
        }
        __syncthreads();
        float o1[4];
#pragma unroll
        for (int cc = 0; cc < 4; cc++) o1[cc] = bo1[4*l2 + cc];
#pragma unroll
        for (int i = 0; i < HF; i++){
            float hvv = sm.go.sh[node][i];
            float4 w4 = *(const float4*)&sm.go.sW1[i*HF + 4*l2];
            o1[0] = fmaf(hvv, w4.x, o1[0]); o1[1] = fmaf(hvv, w4.y, o1[1]);
            o1[2] = fmaf(hvv, w4.z, o1[2]); o1[3] = fmaf(hvv, w4.w, o1[3]);
        }
#pragma unroll
        for (int cc = 0; cc < 4; cc++) sm.go.sh2[node][4*l2 + cc] = leaky(o1[cc]);
        __syncthreads();
        float o2[4];
#pragma unroll
        for (int cc = 0; cc < 4; cc++) o2[cc] = bo2[4*l2 + cc];
#pragma unroll
        for (int i = 0; i < HF; i++){
            float hvv = sm.go.sh2[node][i];
            float4 w4 = *(const float4*)&sm.go.sW2[i*HF + 4*l2];
            o2[0] = fmaf(hvv, w4.x, o2[0]); o2[1] = fmaf(hvv, w4.y, o2[1]);
            o2[2] = fmaf(hvv, w4.z, o2[2]); o2[3] = fmaf(hvv, w4.w, o2[3]);
        }
        __syncthreads();
#pragma unroll
        for (int cc = 0; cc < 4; cc++) sm.go.sh[node][4*l2 + cc] = leaky(o2[cc]);
        __syncthreads();
        if (n < N && l2 < 4){
            float v = bo3[l2];
#pragma unroll
            for (int i = 0; i < HF; i++) v = fmaf(sm.go.sh[node][i], sm.go.sW3[i*4 + l2], v);
            if (l2 == 0) v = sigmoidf(v);
            out[(size_t)n*4 + l2] = v;
        }
    }
}

extern "C" void kernel_launch(void* const* d_in, const int* in_sizes, int n_in,
                              void* d_out, int out_size, void* d_ws, size_t ws_size,
                              hipStream_t stream) {
    const float* x     = (const float*)d_in[0];
    const float* w_in1 = (const float*)d_in[1];
    const float* b_in1 = (const float*)d_in[2];
    const float* w_in2 = (const float*)d_in[3];
    const float* b_in2 = (const float*)d_in[4];
    const float* gamma = (const float*)d_in[5];
    const float* beta  = (const float*)d_in[6];
    const float* wg1   = (const float*)d_in[7];
    const float* bg1   = (const float*)d_in[8];
    const float* wg2   = (const float*)d_in[9];
    const float* bg2   = (const float*)d_in[10];
    const float* wg3   = (const float*)d_in[11];
    const float* bg3   = (const float*)d_in[12];
    const float* wo1   = (const float*)d_in[13];
    const float* bo1   = (const float*)d_in[14];
    const float* wo2   = (const float*)d_in[15];
    const float* bo2   = (const float*)d_in[16];
    const float* wo3   = (const float*)d_in[17];
    const float* bo3   = (const float*)d_in[18];
    const int*   ei    = (const int*)d_in[19];

    int N = in_sizes[0] / 3;
    int E = in_sizes[19] / 2;
    int B = (N + BSZ - 1) >> BSH;          // buckets (782; bin arrays hold 1024)

    char* w = (char*)d_ws;
    size_t o = 0;
    auto alloc = [&](size_t bytes){ size_t r = o; o = (o + bytes + 255) & ~(size_t)255; return r; };
    // ---- zeroed region ----
    float* stats = (float*)(w + alloc(2*HF*sizeof(float)));
    int*   gfill = (int*)  (w + alloc((size_t)B*8*4));
    int*   barv  = (int*)  (w + alloc(512));
    size_t zero_bytes = o;
    // ---- rest ----
    int2*  rowp2 = (int2*) (w + alloc((size_t)N*8));
    float* dis   = (float*)(w + alloc((size_t)N*4));
    int*   ep    = (int*)  (w + alloc((size_t)B*CAP*4));
    __half* bufH = (__half*)(w + alloc((size_t)N*HF*2));
    __half* tA   = (__half*)(w + alloc((size_t)N*HF*2));
    __half* tB   = (__half*)(w + alloc((size_t)N*HF*2));

    hipMemsetAsync(d_ws, 0, zero_bytes, stream);

    const int* src = ei;
    const int* dst = ei + E;
    int NB1 = (N + 255) / 256;
    int NC  = (E + CH - 1) / CH;
    int GN  = (N + 31) / 32;

    // persistent grid sized for guaranteed co-residency (hand-rolled barrier)
    static int s_nblk = 0;
    if (s_nblk == 0){
        int ncu = 256;
        hipDeviceProp_t prop;
        if (hipGetDeviceProperties(&prop, 0) == hipSuccess && prop.multiProcessorCount > 0)
            ncu = prop.multiProcessorCount;
        int nb = 0;
        if (hipOccupancyMaxActiveBlocksPerMultiprocessor(&nb, k_fused, 256, 0) != hipSuccess || nb < 1)
            nb = 2;   // ultra-safe fallback: LDS 38.5KB and VGPR<=128 both allow >=2
        long g = (long)ncu * nb;
        if (g > 2048) g = 2048;
        s_nblk = (int)g;
    }

    k_fused<<<s_nblk, 256, 0, stream>>>(x, w_in1, b_in1, w_in2, b_in2, gamma, beta,
                                        wg1, bg1, wg2, bg2, wg3, bg3,
                                        wo1, bo1, wo2, bo2, wo3, bo3,
                                        src, dst, stats, gfill, barv,
                                        rowp2, dis, ep, bufH, tA, tB,
                                        (float*)d_out, N, E, B, NC, NB1, GN);
}

// Round 9
// 277.424 us; speedup vs baseline: 5.6973x; 3.4768x over previous
//
#include <hip/hip_runtime.h>
#include <hip/hip_fp16.h>

#define HF 32
#define EPS 1e-5f
#define BSH 6
#define BSZ 64           // nodes per bucket
#define CH  16384        // edges per binning block (two-pass, L2-hot re-read)
#define SUBCAP 320       // per-XCD sub-segment capacity (verified r6)
#define CAP (8*SUBCAP)   // bucket segment capacity (2560)
#define FXS 524288.0f    // 2^19 fixed-point scale (range +-4096, quant 1.9e-6)
#define FXI (1.0f/524288.0f)

typedef int vi4 __attribute__((ext_vector_type(4)));

__device__ __forceinline__ float leaky(float v){ return fmaxf(v, 0.01f*v); }
__device__ __forceinline__ float elu1(float v){ return v > 0.f ? v : (expf(v)-1.f); }
__device__ __forceinline__ float sigmoidf(float v){ return 1.f/(1.f+expf(-v)); }

// LESSONS: nt stores on scattered writes -> 143MB writeback (r10). Scattered
// global atomics -> +84MB (r1). Degree-sorted node order -> imbalance (r2).
// FP atomics into LDS (ANY spelling) never lower to ds_add_f32 here: r4
// (unsafeAtomicAdd) and r6 (atomicAdd on __shared__ float) both hit the
// flat/CAS path, 10-30x. Persistent kernel + agent-fence grid barriers ->
// L2 flush per phase, FETCH 2.75x (r7). INT LDS atomics ARE fast (binning
// does 2.5M in <55us) -> fixed-point Q.19 accumulation here. r8 bench was
// an infra failure (container), not a kernel verdict — resubmitted as-is.
__device__ __forceinline__ int4 nt_load_i4(const int* p){
    vi4 v = __builtin_nontemporal_load((const vi4*)p);
    return make_int4(v.x, v.y, v.z, v.w);
}

// accumulate 8 halfs (16B row quarter) into __shared__ int Q.19 accumulator
// via native ds_add_u32.
__device__ __forceinline__ void accum8_fx(int* a, float4 v){
    const __half2* p = (const __half2*)&v;
#pragma unroll
    for (int k = 0; k < 4; k++){
        float2 f = __half22float2(p[k]);
        atomicAdd(a + 2*k,     __float2int_rn(f.x * FXS));
        atomicAdd(a + 2*k + 1, __float2int_rn(f.y * FXS));
    }
}

// ===== fused: edge binning (two-pass, bin blocks FIRST) | MLP + BN stats ====
union SMem {
    struct {
        float sW1[3*HF]; float sB1[HF]; float sW2[HF*HF]; float sB2[HF];
        float sh[256][33];
    } mlp;
    struct { int lcnt[2048]; int lbase[2048]; int lpos[2048]; } bin;
};

__global__ __launch_bounds__(256)
void k_mlp_bin(const float* __restrict__ x,
               const float* __restrict__ w1, const float* __restrict__ b1,
               const float* __restrict__ w2, const float* __restrict__ b2,
               __half* __restrict__ h, float* __restrict__ stats,
               const int* __restrict__ src, const int* __restrict__ dst,
               int* __restrict__ gfill, int* __restrict__ ep,
               int N, int E, int B, int NC){
    __shared__ SMem sm;
    int t = threadIdx.x;
    if ((int)blockIdx.x < NC){
        // ------- binning: two-pass (count from nt stream, reserve, scatter) -
        int bid = blockIdx.x;
        for (int i = t; i < B; i += 256){ sm.bin.lcnt[i] = 0; sm.bin.lpos[i] = 0; }
        __syncthreads();
        int base = bid * CH;
        int xcd = bid & 7;
        bool full = (base + CH <= E);
        if (full){
            for (int i = 0; i < 16; i++){
                int4 d4 = nt_load_i4(dst + base + (t + i*256)*4);
                atomicAdd(&sm.bin.lcnt[d4.x >> BSH], 1);
                atomicAdd(&sm.bin.lcnt[d4.y >> BSH], 1);
                atomicAdd(&sm.bin.lcnt[d4.z >> BSH], 1);
                atomicAdd(&sm.bin.lcnt[d4.w >> BSH], 1);
            }
        } else {
            for (int i = 0; i < 64; i++){
                int e = base + t + i*256;
                if (e < E) atomicAdd(&sm.bin.lcnt[dst[e] >> BSH], 1);
            }
        }
        __syncthreads();
        // reserve contiguous range in this block's xcd sub-segment per bucket
        for (int i = t; i < B; i += 256){
            int c = sm.bin.lcnt[i];
            sm.bin.lbase[i] = c ? (i*CAP + xcd*SUBCAP + atomicAdd(&gfill[i*8 + xcd], c)) : 0;
        }
        __syncthreads();
        // scatter: re-read edges (L2-hot second pass)
        if (full){
            for (int i = 0; i < 16; i++){
                int idx = base + (t + i*256)*4;
                int4 d4 = *(const int4*)(dst + idx);
                int4 s4 = *(const int4*)(src + idx);
                int dd[4] = {d4.x, d4.y, d4.z, d4.w};
                int ss[4] = {s4.x, s4.y, s4.z, s4.w};
#pragma unroll
                for (int k = 0; k < 4; k++){
                    int bb = dd[k] >> BSH;
                    int p = sm.bin.lbase[bb] + atomicAdd(&sm.bin.lpos[bb], 1);
                    ep[p] = (ss[k] << BSH) | (dd[k] & (BSZ-1));
                }
            }
        } else {
            for (int i = 0; i < 64; i++){
                int e = base + t + i*256;
                if (e < E){
                    int d = dst[e], s = src[e];
                    int bb = d >> BSH;
                    int p = sm.bin.lbase[bb] + atomicAdd(&sm.bin.lpos[bb], 1);
                    ep[p] = (s << BSH) | (d & (BSZ-1));
                }
            }
        }
    } else {
        // ---------------- MLP + BN stats ----------------
        for (int i = t; i < 3*HF; i += 256) sm.mlp.sW1[i] = w1[i];
        if (t < HF){ sm.mlp.sB1[t] = b1[t]; sm.mlp.sB2[t] = b2[t]; }
        for (int i = t; i < HF*HF; i += 256) sm.mlp.sW2[i] = w2[i];
        __syncthreads();
        int n = (blockIdx.x - NC)*256 + t;
        float h2[HF];
        if (n < N){
            float x0 = x[(size_t)n*3], x1 = x[(size_t)n*3+1], x2 = x[(size_t)n*3+2];
            float h1[HF];
#pragma unroll
            for (int j = 0; j < HF; j++){
                float v = fmaf(x0, sm.mlp.sW1[j], fmaf(x1, sm.mlp.sW1[HF+j],
                          fmaf(x2, sm.mlp.sW1[2*HF+j], sm.mlp.sB1[j])));
                h1[j] = leaky(v);
            }
#pragma unroll
            for (int j = 0; j < HF; j++){
                float v = sm.mlp.sB2[j];
#pragma unroll
                for (int i = 0; i < HF; i++) v = fmaf(h1[i], sm.mlp.sW2[i*HF+j], v);
                h2[j] = leaky(v);
            }
            float4* hv = (float4*)(h + (size_t)n*HF);
#pragma unroll
            for (int jb = 0; jb < 4; jb++){
                __half2 hh[4];
#pragma unroll
                for (int k = 0; k < 4; k++)
                    hh[k] = __float22half2_rn(make_float2(h2[jb*8+2*k], h2[jb*8+2*k+1]));
                hv[jb] = *(float4*)hh;
            }
        } else {
#pragma unroll
            for (int j = 0; j < HF; j++) h2[j] = 0.f;
        }
#pragma unroll
        for (int j = 0; j < HF; j++) sm.mlp.sh[t][j] = h2[j];
        __syncthreads();
        int f = t & 31, g = t >> 5;
        float s = 0.f, ss = 0.f;
        for (int i = 0; i < 32; i++){
            float v = sm.mlp.sh[g*32 + i][f];
            s += v; ss += v*v;
        }
        __syncthreads();
        sm.mlp.sh[g][f] = s; sm.mlp.sh[8+g][f] = ss;
        __syncthreads();
        if (t < HF){
            float a = 0.f, b = 0.f;
#pragma unroll
            for (int g2 = 0; g2 < 8; g2++){ a += sm.mlp.sh[g2][t]; b += sm.mlp.sh[8+g2][t]; }
            atomicAdd(&stats[t], a);
            atomicAdd(&stats[HF+t], b);
        }
    }
}

// ===== per-bucket: degree count + segment compaction + BN + t1 (r6, OK) =====
__global__ __launch_bounds__(256)
void k_deg_t1(int* __restrict__ ep, const int* __restrict__ gfill,
              int* __restrict__ bcnt, float* __restrict__ dis,
              const __half* __restrict__ h, const float* __restrict__ stats,
              const float* __restrict__ gamma, const float* __restrict__ beta,
              const float* __restrict__ W, __half* __restrict__ tout,
              int N, int B){
    __shared__ union { int sep[CAP]; float hsh[BSZ][HF+1]; } u;
    __shared__ int lcnt[BSZ];
    __shared__ float sW[HF*HF];
    __shared__ float sscale[HF], sshift[HF];
    int t = threadIdx.x;
    int b = blockIdx.x;
    for (int i = t; i < HF*HF; i += 256) sW[i] = W[i];
    if (t < HF){
        float inv = 1.0f/(float)N;
        float mu  = stats[t]*inv;
        float var = stats[HF+t]*inv - mu*mu;
        float rs  = rsqrtf(var + EPS);
        float sc  = rs*gamma[t];
        sscale[t] = sc;
        sshift[t] = beta[t] - mu*sc;
    }
    if (t < BSZ) lcnt[t] = 0;
    int cx[8], coff[8], cnt = 0;
#pragma unroll
    for (int xx = 0; xx < 8; xx++){ cx[xx] = gfill[b*8 + xx]; coff[xx] = cnt; cnt += cx[xx]; }
    int base = b*CAP;
    __syncthreads();
#pragma unroll
    for (int xx = 0; xx < 8; xx++)
        for (int j = t; j < cx[xx]; j += 256) u.sep[coff[xx] + j] = ep[base + xx*SUBCAP + j];
    __syncthreads();
    for (int e = t; e < cnt; e += 256) atomicAdd(&lcnt[u.sep[e] & (BSZ-1)], 1);
    for (int e = t; e < cnt; e += 256) ep[base + e] = u.sep[e];   // compact
    if (t == 0) bcnt[b] = cnt;
    __syncthreads();
    // ------- BN + t1: 4 threads per node, 8 features each -------------------
    int nloc = t >> 2, q = t & 3;
    int n = b*BSZ + nloc;
    float dloc = 0.f;
    if (n < N){
        dloc = rsqrtf((float)lcnt[nloc] + 1.0f);
        if (q == 0) dis[n] = dloc;
        float4 raw = ((const float4*)h)[(size_t)n*4 + q];
        const __half2* p2 = (const __half2*)&raw;
#pragma unroll
        for (int k = 0; k < 4; k++){
            float2 f2 = __half22float2(p2[k]);
            int f = 8*q + 2*k;
            u.hsh[nloc][f]   = fmaf(f2.x, sscale[f],   sshift[f]);
            u.hsh[nloc][f+1] = fmaf(f2.y, sscale[f+1], sshift[f+1]);
        }
    }
    __syncthreads();
    if (n < N){
        int fo = 8*q;
        float o[8] = {0.f,0.f,0.f,0.f,0.f,0.f,0.f,0.f};
#pragma unroll
        for (int i = 0; i < HF; i++){
            float vi = u.hsh[nloc][i];
            float4 w0 = *(const float4*)&sW[i*HF + fo];
            float4 w1 = *(const float4*)&sW[i*HF + fo + 4];
            o[0] = fmaf(vi, w0.x, o[0]); o[1] = fmaf(vi, w0.y, o[1]);
            o[2] = fmaf(vi, w0.z, o[2]); o[3] = fmaf(vi, w0.w, o[3]);
            o[4] = fmaf(vi, w1.x, o[4]); o[5] = fmaf(vi, w1.y, o[5]);
            o[6] = fmaf(vi, w1.z, o[6]); o[7] = fmaf(vi, w1.w, o[7]);
        }
        __half2 hh[4];
#pragma unroll
        for (int k = 0; k < 4; k++)
            hh[k] = __float22half2_rn(make_float2(o[2*k]*dloc, o[2*k+1]*dloc));
        ((float4*)tout)[(size_t)n*4 + q] = *(float4*)hh;
    }
}

// ===== edge-parallel gather per bucket (ds_add_u32 Q.19) + finish + xform ===
__global__ __launch_bounds__(256)
void k_gather_t(const __half* __restrict__ tin, const int* __restrict__ ep,
                const int* __restrict__ bcnt, const float* __restrict__ dis,
                const float* __restrict__ bias, const float* __restrict__ W,
                __half* __restrict__ tout, int N){
    __shared__ int iacc[BSZ][HF+1];
    __shared__ float sW[HF*HF];
    float* facc = (float*)iacc;             // reused as float after finish
    int t = threadIdx.x, b = blockIdx.x;
    for (int i = t; i < HF*HF; i += 256) sW[i] = W[i];
    for (int i = t; i < BSZ*(HF+1); i += 256) ((int*)iacc)[i] = 0;
    int cnt = bcnt[b];
    int base = b*CAP;
    __syncthreads();
    int g = t >> 2, l = t & 3;
    const float4* tv = (const float4*)tin;
    int j = g;
    for (; j + 64 < cnt; j += 128){
        int p0 = ep[base + j], p1 = ep[base + j + 64];
        float4 r0 = tv[(size_t)(p0 >> BSH)*4 + l];
        float4 r1 = tv[(size_t)(p1 >> BSH)*4 + l];
        accum8_fx(&iacc[p0 & (BSZ-1)][8*l], r0);
        accum8_fx(&iacc[p1 & (BSZ-1)][8*l], r1);
    }
    for (; j < cnt; j += 64){
        int p0 = ep[base + j];
        float4 r0 = tv[(size_t)(p0 >> BSH)*4 + l];
        accum8_fx(&iacc[p0 & (BSZ-1)][8*l], r0);
    }
    __syncthreads();
    // ------- finish: 4 threads/node: fx->f32, +self, *dis, +bias, elu -------
    int nloc = t >> 2, q = t & 3;
    int n = b*BSZ + nloc;
    float dv = 0.f;
    float fin[8];
    if (n < N){
        dv = dis[n];
        float4 s0 = tv[(size_t)n*4 + q];
        const __half2* ph = (const __half2*)&s0;
#pragma unroll
        for (int k = 0; k < 4; k++){
            float2 f2 = __half22float2(ph[k]);
            int f = 8*q + 2*k;
            float a0 = (float)iacc[nloc][f]   * FXI + f2.x;
            float a1 = (float)iacc[nloc][f+1] * FXI + f2.y;
            fin[2*k]   = elu1(fmaf(dv, a0, bias[f]));
            fin[2*k+1] = elu1(fmaf(dv, a1, bias[f+1]));
        }
    }
    __syncthreads();
    if (n < N){
#pragma unroll
        for (int k = 0; k < 8; k++) facc[nloc*(HF+1) + 8*q + k] = fin[k];
    }
    __syncthreads();
    // ------- transform: o = (hnext @ W) * dis, fp16 store -------------------
    if (n < N){
        int fo = 8*q;
        float o[8] = {0.f,0.f,0.f,0.f,0.f,0.f,0.f,0.f};
#pragma unroll
        for (int i = 0; i < HF; i++){
            float hv = facc[nloc*(HF+1) + i];
            float4 w0 = *(const float4*)&sW[i*HF + fo];
            float4 w1 = *(const float4*)&sW[i*HF + fo + 4];
            o[0] = fmaf(hv, w0.x, o[0]); o[1] = fmaf(hv, w0.y, o[1]);
            o[2] = fmaf(hv, w0.z, o[2]); o[3] = fmaf(hv, w0.w, o[3]);
            o[4] = fmaf(hv, w1.x, o[4]); o[5] = fmaf(hv, w1.y, o[5]);
            o[6] = fmaf(hv, w1.z, o[6]); o[7] = fmaf(hv, w1.w, o[7]);
        }
        __half2 hh[4];
#pragma unroll
        for (int k = 0; k < 4; k++)
            hh[k] = __float22half2_rn(make_float2(o[2*k]*dv, o[2*k+1]*dv));
        ((float4*)tout)[(size_t)n*4 + q] = *(float4*)hh;
    }
}

// ===== edge-parallel gather + elu + output MLP + sigmoid col 0 ==============
__global__ __launch_bounds__(256)
void k_gather_out(const __half* __restrict__ tin, const int* __restrict__ ep,
                  const int* __restrict__ bcnt, const float* __restrict__ dis,
                  const float* __restrict__ bg3,
                  const float* __restrict__ wo1, const float* __restrict__ bo1,
                  const float* __restrict__ wo2, const float* __restrict__ bo2,
                  const float* __restrict__ wo3, const float* __restrict__ bo3,
                  float* __restrict__ out, int N){
    __shared__ int iacc[BSZ][HF+1];
    __shared__ float sW1[HF*HF], sW2[HF*HF], sW3[HF*4];
    float* facc = (float*)iacc;
    int t = threadIdx.x, b = blockIdx.x;
    for (int i = t; i < HF*HF; i += 256){ sW1[i] = wo1[i]; sW2[i] = wo2[i]; }
    if (t < HF*4) sW3[t] = wo3[t];
    for (int i = t; i < BSZ*(HF+1); i += 256) ((int*)iacc)[i] = 0;
    int cnt = bcnt[b];
    int base = b*CAP;
    __syncthreads();
    int g = t >> 2, l = t & 3;
    const float4* tv = (const float4*)tin;
    int j = g;
    for (; j + 64 < cnt; j += 128){
        int p0 = ep[base + j], p1 = ep[base + j + 64];
        float4 r0 = tv[(size_t)(p0 >> BSH)*4 + l];
        float4 r1 = tv[(size_t)(p1 >> BSH)*4 + l];
        accum8_fx(&iacc[p0 & (BSZ-1)][8*l], r0);
        accum8_fx(&iacc[p1 & (BSZ-1)][8*l], r1);
    }
    for (; j < cnt; j += 64){
        int p0 = ep[base + j];
        float4 r0 = tv[(size_t)(p0 >> BSH)*4 + l];
        accum8_fx(&iacc[p0 & (BSZ-1)][8*l], r0);
    }
    __syncthreads();
    int nloc = t >> 2, q = t & 3;
    int n = b*BSZ + nloc;
    // finish: fx->f32 + self + dis + bg3 + elu -> facc (h for output MLP)
    float fin[8];
    if (n < N){
        float dv = dis[n];
        float4 s0 = tv[(size_t)n*4 + q];
        const __half2* ph = (const __half2*)&s0;
#pragma unroll
        for (int k = 0; k < 4; k++){
            float2 f2 = __half22float2(ph[k]);
            int f = 8*q + 2*k;
            float a0 = (float)iacc[nloc][f]   * FXI + f2.x;
            float a1 = (float)iacc[nloc][f+1] * FXI + f2.y;
            fin[2*k]   = elu1(fmaf(dv, a0, bg3[f]));
            fin[2*k+1] = elu1(fmaf(dv, a1, bg3[f+1]));
        }
    }
    __syncthreads();
    if (n < N){
#pragma unroll
        for (int k = 0; k < 8; k++) facc[nloc*(HF+1) + 8*q + k] = fin[k];
    }
    __syncthreads();
    // o1 = leaky(h @ Wo1 + bo1)
    float o1[8];
    if (n < N){
        int fo = 8*q;
#pragma unroll
        for (int c = 0; c < 8; c++) o1[c] = bo1[fo + c];
#pragma unroll
        for (int i = 0; i < HF; i++){
            float hv = facc[nloc*(HF+1) + i];
            float4 w0 = *(const float4*)&sW1[i*HF + fo];
            float4 w1 = *(const float4*)&sW1[i*HF + fo + 4];
            o1[0] = fmaf(hv, w0.x, o1[0]); o1[1] = fmaf(hv, w0.y, o1[1]);
            o1[2] = fmaf(hv, w0.z, o1[2]); o1[3] = fmaf(hv, w0.w, o1[3]);
            o1[4] = fmaf(hv, w1.x, o1[4]); o1[5] = fmaf(hv, w1.y, o1[5]);
            o1[6] = fmaf(hv, w1.z, o1[6]); o1[7] = fmaf(hv, w1.w, o1[7]);
        }
    }
    __syncthreads();
    if (n < N){
        int fo = 8*q;
#pragma unroll
        for (int c = 0; c < 8; c++) facc[nloc*(HF+1) + fo + c] = leaky(o1[c]);
    }
    __syncthreads();
    // o2 = leaky(o1 @ Wo2 + bo2)
    float o2[8];
    if (n < N){
        int fo = 8*q;
#pragma unroll
        for (int c = 0; c < 8; c++) o2[c] = bo2[fo + c];
#pragma unroll
        for (int i = 0; i < HF; i++){
            float hv = facc[nloc*(HF+1) + i];
            float4 w0 = *(const float4*)&sW2[i*HF + fo];
            float4 w1 = *(const float4*)&sW2[i*HF + fo + 4];
            o2[0] = fmaf(hv, w0.x, o2[0]); o2[1] = fmaf(hv, w0.y, o2[1]);
            o2[2] = fmaf(hv, w0.z, o2[2]); o2[3] = fmaf(hv, w0.w, o2[3]);
            o2[4] = fmaf(hv, w1.x, o2[4]); o2[5] = fmaf(hv, w1.y, o2[5]);
            o2[6] = fmaf(hv, w1.z, o2[6]); o2[7] = fmaf(hv, w1.w, o2[7]);
        }
    }
    __syncthreads();
    if (n < N){
        int fo = 8*q;
#pragma unroll
        for (int c = 0; c < 8; c++) facc[nloc*(HF+1) + fo + c] = leaky(o2[c]);
    }
    __syncthreads();
    // final: 4 threads/node, 1 output each
    if (n < N){
        float v = bo3[q];
#pragma unroll
        for (int i = 0; i < HF; i++) v = fmaf(facc[nloc*(HF+1) + i], sW3[i*4 + q], v);
        if (q == 0) v = sigmoidf(v);
        out[(size_t)n*4 + q] = v;
    }
}

extern "C" void kernel_launch(void* const* d_in, const int* in_sizes, int n_in,
                              void* d_out, int out_size, void* d_ws, size_t ws_size,
                              hipStream_t stream) {
    const float* x     = (const float*)d_in[0];
    const float* w_in1 = (const float*)d_in[1];
    const float* b_in1 = (const float*)d_in[2];
    const float* w_in2 = (const float*)d_in[3];
    const float* b_in2 = (const float*)d_in[4];
    const float* gamma = (const float*)d_in[5];
    const float* beta  = (const float*)d_in[6];
    const float* wg1   = (const float*)d_in[7];
    const float* bg1   = (const float*)d_in[8];
    const float* wg2   = (const float*)d_in[9];
    const float* bg2   = (const float*)d_in[10];
    const float* wg3   = (const float*)d_in[11];
    const float* bg3   = (const float*)d_in[12];
    const float* wo1   = (const float*)d_in[13];
    const float* bo1   = (const float*)d_in[14];
    const float* wo2   = (const float*)d_in[15];
    const float* bo2   = (const float*)d_in[16];
    const float* wo3   = (const float*)d_in[17];
    const float* bo3   = (const float*)d_in[18];
    const int*   ei    = (const int*)d_in[19];

    int N = in_sizes[0] / 3;
    int E = in_sizes[19] / 2;
    int B = (N + BSZ - 1) >> BSH;          // buckets (1563; bin arrays hold 2048)

    char* w = (char*)d_ws;
    size_t o = 0;
    auto alloc = [&](size_t bytes){ size_t r = o; o = (o + bytes + 255) & ~(size_t)255; return r; };
    // ---- zeroed region ----
    float* stats = (float*)(w + alloc(2*HF*sizeof(float)));
    int*   gfill = (int*)  (w + alloc((size_t)B*8*4));
    size_t zero_bytes = o;
    // ---- rest ----
    int*   bcnt  = (int*)  (w + alloc((size_t)B*4));
    float* dis   = (float*)(w + alloc((size_t)N*4));
    int*   ep    = (int*)  (w + alloc((size_t)B*CAP*4));
    __half* bufH = (__half*)(w + alloc((size_t)N*HF*2));
    __half* tA   = (__half*)(w + alloc((size_t)N*HF*2));
    __half* tB   = (__half*)(w + alloc((size_t)N*HF*2));

    hipMemsetAsync(d_ws, 0, zero_bytes, stream);

    const int* src = ei;
    const int* dst = ei + E;
    int NB1 = (N + 255) / 256;
    int NC  = (E + CH - 1) / CH;

    k_mlp_bin<<<NC + NB1, 256, 0, stream>>>(x, w_in1, b_in1, w_in2, b_in2, bufH, stats,
                                            src, dst, gfill, ep, N, E, B, NC);
    k_deg_t1<<<B, 256, 0, stream>>>(ep, gfill, bcnt, dis,
                                    bufH, stats, gamma, beta, wg1, tA, N, B);
    k_gather_t<<<B, 256, 0, stream>>>(tA, ep, bcnt, dis, bg1, wg2, tB, N);
    k_gather_t<<<B, 256, 0, stream>>>(tB, ep, bcnt, dis, bg2, wg3, tA, N);
    k_gather_out<<<B, 256, 0, stream>>>(tA, ep, bcnt, dis, bg3,
                                        wo1, bo1, wo2, bo2, wo3, bo3, (float*)d_out, N);
}